// Round 10
// baseline (27.578 us; speedup 1.0000x reference)
//
#include <hip/hip_runtime.h>
#include <hip/hip_fp16.h>

#define NUM_CAMS 6
#define C_FEAT   64
#define HF       16
#define WF       44
#define NPTS     (128*128*8)   // 131072
#define FEAT_ELEMS (NUM_CAMS*C_FEAT*HF*WF)  // 270336
#define PPB      64            // points per block
#define NTHREADS 512

// ---- kernel 1: flat transpose+fp16 convert (full grid) + proj matmul ----
__global__ __launch_bounds__(256) void uvt_prep(const float* __restrict__ in,
                                                const float* __restrict__ ego2cam,
                                                const float* __restrict__ cam2img,
                                                __half* __restrict__ featsT,
                                                float* __restrict__ projws) {
    const int blk = blockIdx.x;
    if (blk < FEAT_ELEMS / 256) {
        const int g   = blk * 256 + threadIdx.x;
        const int c   = g & 63;
        const int pix = g >> 6;
        const int x   = pix % WF;
        const int t2  = pix / WF;
        const int y   = t2 % HF;
        const int n   = t2 / HF;
        featsT[g] = __float2half(in[((n * C_FEAT + c) * HF + y) * WF + x]);
    } else {
        const int t = threadIdx.x;
        if (t < NUM_CAMS * 12) {
            const int cam = t / 12, e = t - cam * 12;
            const int i = e >> 2, j = e & 3;
            const float* A = cam2img + cam * 16;
            const float* B = ego2cam + cam * 16;
            float sum = 0.f;
            #pragma unroll
            for (int k = 0; k < 4; ++k) sum += A[i*4 + k] * B[k*4 + j];
            projws[cam * 12 + e] = sum;
        }
    }
}

// packed per (point,cam) sampling params: 16 B -> one ds_read_b128
struct alignas(16) PCP {
    __half2  wA;     // {w00, w10}
    __half2  wB;     // {w01, w11}
    int      base;   // half-elem offset of (cam,y0,x0) pixel; 0 if invalid
    unsigned flags;  // dx | (dy<<16) | (valid<<31); dx=dy=0 if invalid/OOB
};

// ---- kernel 2: project + branchless pipelined bilinear + fuse ----
// 512 threads = 64 points x 8 channel-octs; oct = tid&7 (16B), pl = tid>>3
__global__ __launch_bounds__(NTHREADS, 4) void uvt_fuse(
    const __half* __restrict__ featsT,  // (6,16,44,64) fp16
    const float* __restrict__ projws,   // (6,3,4)
    const float* __restrict__ vox,      // (3, NPTS)
    float* __restrict__ out)            // (64, NPTS)
{
    // LDS union: s_pc (6 KB) lives inside s_out's 16.6 KB footprint
    __shared__ __align__(16) char ldsbuf[PPB * (C_FEAT + 1) * sizeof(float)];
    PCP   (*s_pc)[PPB]         = (PCP (*)[PPB])ldsbuf;
    float (*s_out)[C_FEAT + 1] = (float (*)[C_FEAT + 1])ldsbuf;

    const int tid = threadIdx.x;
    const int p0  = blockIdx.x * PPB;

    // ---- phase 1: per (point,cam) params; one cam per wave -> scalar proj ----
    if (tid < NUM_CAMS * PPB) {         // 384 threads, 6 waves
        const int cam = __builtin_amdgcn_readfirstlane(tid >> 6);
        const int lp  = tid & 63;
        const int p   = p0 + lp;
        const float* M = projws + cam * 12;

        const float px = vox[p];
        const float py = vox[NPTS + p];
        const float pz = vox[2 * NPTS + p];
        const float ud = M[0]*px + M[1]*py + M[2]*pz  + M[3];
        const float vd = M[4]*px + M[5]*py + M[6]*pz  + M[7];
        const float d  = M[8]*px + M[9]*py + M[10]*pz + M[11];
        const float id = 1.0f / (d + 1e-6f);
        const float u  = ud * id;
        const float v  = vd * id;
        const bool valid = (d > 0.1f) && (u >= 0.f) && (u <= 703.f)
                                      && (v >= 0.f) && (v <= 255.f);
        PCP pc;
        if (valid) {
            const float x  = u * 0.0625f;
            const float y  = v * 0.0625f;
            const float xf = floorf(x), yf = floorf(y);
            const int   x0 = (int)xf,   y0 = (int)yf;
            const float wx1 = x - xf,  wy1 = y - yf;
            const float wx0 = 1.f - wx1, wy0 = 1.f - wy1;
            const bool bx = (x0 < WF - 1);
            const bool by = (y0 < HF - 1);
            pc.wA = __halves2half2(__float2half(wx0 * wy0),
                                   __float2half(bx ? wx1 * wy0 : 0.f));
            pc.wB = __halves2half2(__float2half(by ? wx0 * wy1 : 0.f),
                                   __float2half((bx && by) ? wx1 * wy1 : 0.f));
            pc.base  = ((cam * HF + y0) * WF + x0) << 6;
            pc.flags = (bx ? 64u : 0u)
                     | ((by ? (unsigned)(WF * C_FEAT) : 0u) << 16)
                     | 0x80000000u;
        } else {
            pc.wA = pc.wB = __halves2half2(__float2half(0.f), __float2half(0.f));
            pc.base = 0; pc.flags = 0u;
        }
        s_pc[cam][lp] = pc;          // one ds_write_b128
    }
    __syncthreads();

    // ---- phase 2: branchless, 3-cam-deep pipelined gather ----
    const int oct = tid & 7;
    const int pl  = tid >> 3;

    PCP pc[NUM_CAMS];
    #pragma unroll
    for (int cam = 0; cam < NUM_CAMS; ++cam) pc[cam] = s_pc[cam][pl];

    int cnt = 0;
    #pragma unroll
    for (int cam = 0; cam < NUM_CAMS; ++cam) cnt += (int)(pc[cam].flags >> 31);
    const float inv = 1.0f / (float)(cnt > 0 ? cnt : 1);

    float2 a0 = {0.f,0.f}, a1 = {0.f,0.f}, a2 = {0.f,0.f}, a3 = {0.f,0.f};

    uint4 rA[4], rB[4], rC[4];

    #define ISSUE(dst, c_) { \
        const unsigned fl_ = pc[c_].flags; \
        const int dx_ = (int)(fl_ & 0xFFFFu); \
        const int dy_ = (int)((fl_ >> 16) & 0x7FFFu); \
        const __half* b_ = featsT + pc[c_].base + (oct << 3); \
        dst[0] = *(const uint4*)(b_); \
        dst[1] = *(const uint4*)(b_ + dx_); \
        dst[2] = *(const uint4*)(b_ + dy_); \
        dst[3] = *(const uint4*)(b_ + dx_ + dy_); }

    #define BC(u_) __builtin_bit_cast(__half2, u_)
    #define CONSUME(src, c_) { \
        const __half2 w00_ = __low2half2(pc[c_].wA); \
        const __half2 w10_ = __high2half2(pc[c_].wA); \
        const __half2 w01_ = __low2half2(pc[c_].wB); \
        const __half2 w11_ = __high2half2(pc[c_].wB); \
        __half2 s0_ = __hmul2(w00_, BC(src[0].x)); \
        s0_ = __hfma2(w10_, BC(src[1].x), s0_); \
        s0_ = __hfma2(w01_, BC(src[2].x), s0_); \
        s0_ = __hfma2(w11_, BC(src[3].x), s0_); \
        __half2 s1_ = __hmul2(w00_, BC(src[0].y)); \
        s1_ = __hfma2(w10_, BC(src[1].y), s1_); \
        s1_ = __hfma2(w01_, BC(src[2].y), s1_); \
        s1_ = __hfma2(w11_, BC(src[3].y), s1_); \
        __half2 s2_ = __hmul2(w00_, BC(src[0].z)); \
        s2_ = __hfma2(w10_, BC(src[1].z), s2_); \
        s2_ = __hfma2(w01_, BC(src[2].z), s2_); \
        s2_ = __hfma2(w11_, BC(src[3].z), s2_); \
        __half2 s3_ = __hmul2(w00_, BC(src[0].w)); \
        s3_ = __hfma2(w10_, BC(src[1].w), s3_); \
        s3_ = __hfma2(w01_, BC(src[2].w), s3_); \
        s3_ = __hfma2(w11_, BC(src[3].w), s3_); \
        const float2 f0_ = __half22float2(s0_); \
        const float2 f1_ = __half22float2(s1_); \
        const float2 f2_ = __half22float2(s2_); \
        const float2 f3_ = __half22float2(s3_); \
        a0.x += f0_.x; a0.y += f0_.y; \
        a1.x += f1_.x; a1.y += f1_.y; \
        a2.x += f2_.x; a2.y += f2_.y; \
        a3.x += f3_.x; a3.y += f3_.y; }

    ISSUE(rA, 0); ISSUE(rB, 1); ISSUE(rC, 2);
    CONSUME(rA, 0); ISSUE(rA, 3);
    CONSUME(rB, 1); ISSUE(rB, 4);
    CONSUME(rC, 2); ISSUE(rC, 5);
    CONSUME(rA, 3); CONSUME(rB, 4); CONSUME(rC, 5);

    #undef ISSUE
    #undef CONSUME
    #undef BC

    __syncthreads();   // all s_pc reads done before s_out overwrites union

    // ---- phase 3: transpose through LDS, 256 B-coalesced stores ----
    const int cb = oct << 3;
    s_out[pl][cb + 0] = a0.x * inv;
    s_out[pl][cb + 1] = a0.y * inv;
    s_out[pl][cb + 2] = a1.x * inv;
    s_out[pl][cb + 3] = a1.y * inv;
    s_out[pl][cb + 4] = a2.x * inv;
    s_out[pl][cb + 5] = a2.y * inv;
    s_out[pl][cb + 6] = a3.x * inv;
    s_out[pl][cb + 7] = a3.y * inv;
    __syncthreads();

    #pragma unroll
    for (int i = 0; i < 8; ++i) {
        const int idx = tid + NTHREADS * i;   // 0..4095
        const int c   = idx >> 6;             // channel
        const int lp  = idx & 63;             // point (64 consecutive per wave)
        out[c * NPTS + p0 + lp] = s_out[lp][c];
    }
}

// ---------------------------------------------------------------------------
extern "C" void kernel_launch(void* const* d_in, const int* in_sizes, int n_in,
                              void* d_out, int out_size, void* d_ws, size_t ws_size,
                              hipStream_t stream) {
    const float* img_feats = (const float*)d_in[0];  // (6,64,16,44)
    const float* ego2cam   = (const float*)d_in[1];  // (6,4,4)
    const float* cam2img   = (const float*)d_in[2];  // (6,4,4)
    const float* vox       = (const float*)d_in[3];  // (3,8,128,128)
    float* out = (float*)d_out;                      // (1,64,8,128,128)

    __half* featsT = (__half*)d_ws;                  // 270336 halves
    float*  projws = (float*)((char*)d_ws + FEAT_ELEMS * sizeof(__half)); // 72 floats

    uvt_prep<<<FEAT_ELEMS / 256 + 1, 256, 0, stream>>>(img_feats, ego2cam, cam2img,
                                                       featsT, projws);
    uvt_fuse<<<NPTS / PPB, NTHREADS, 0, stream>>>(featsT, projws, vox, out);
}